// Round 6
// baseline (12664.675 us; speedup 1.0000x reference)
//
#include <hip/hip_runtime.h>
#include <hip/hip_fp16.h>
#include <math.h>

#define BB 512
#define HH 256
#define SS 168
#define TT 24
#define NBLK 256
#define NTHR 256
typedef unsigned long long ull;
#define BH 131072ull  // 512*256

// ---- int area (from ws): group flags [g*1024 .. ), control at 8192 ----
//  per group g (stride 1024): if0: t*2+h (tgt 8) | if1: 512+s (tgt 16)
//  ifa: 704+t (tgt 32) | ifh0: 736+t (tgt 16) | ifh1: 768+t (tgt 16) | ifp: 900 (tgt 32)
// control: cnt[8]@8192, rcnt@8200, rdone@8201, scnt@8202, sdone@8203,
//          smask@8204, sidx@8205, clm[256]@8208   (zeroed to 8464)
// ---- float offsets from fb = (float*)ws + 65536 ----
#define O_Y0  0ull        // y0 ring, 4 slots (4*BH)
#define O_H1  524288ull   // h1 ring, 2 slots
#define O_H0  786432ull   // dec h0 ring, 2 slots
#define O_CTX 1048576ull  // 512 x 288 (cols 0..255 ctx, col 256 pred)
#define O_WT0 1196032ull  // enc l0 W^T [272][1024]
#define O_WT1 1474560ull  // enc l1 W^T [512][1024]
#define O_WD0 1998848ull  // dec c0 W^T [513][1024]
#define O_WD1 2524160ull  // dec c1 W^T [512][1024]
#define O_WDT 3048448ull  // Wd^T [256][256]
#define O_BP  3113984ull  // packed biases 4x1024 (e0,e1,d0,d1)
#define O_E16 3118080ull  // half[512][168][256]
#define O_P16 14128128ull // half[512][168][256]

__device__ __forceinline__ float sigf(float x) { return 1.f / (1.f + expf(-x)); }

#define AR __ATOMIC_RELAXED
#define SCA __HIP_MEMORY_SCOPE_AGENT
__device__ __forceinline__ int aLd(int* p) { return __hip_atomic_load(p, AR, SCA); }
__device__ __forceinline__ void aSt(int* p, int v) { __hip_atomic_store(p, v, AR, SCA); }
__device__ __forceinline__ int aAdd(int* p, int v) { return __hip_atomic_fetch_add(p, v, AR, SCA); }
__device__ __forceinline__ void aOr(int* p, int v) { __hip_atomic_fetch_or(p, v, AR, SCA); }

// ---- UC transport (L3/coherence-point; R5 path — fallback for spill groups) ----
__device__ __forceinline__ float2 ld2(const float* p) {
  ull raw = __hip_atomic_load((const ull*)p, AR, SCA);
  float2 v; v.x = __uint_as_float((unsigned)raw); v.y = __uint_as_float((unsigned)(raw >> 32));
  return v;
}
__device__ __forceinline__ float ld1(const float* p) {
  unsigned raw = __hip_atomic_load((const unsigned*)p, AR, SCA);
  return __uint_as_float(raw);
}
__device__ __forceinline__ void st1(float* p, float v) {
  __hip_atomic_store((unsigned*)p, __float_as_uint(v), AR, SCA);
}
__device__ __forceinline__ void sth(__half* p, __half v) {
  __hip_atomic_store((unsigned short*)p, __half_as_ushort(v), AR, SCA);
}

// ---- mode-aware transport: local mode = plain store (dirty XCD L2) + sc0
// load (L1-bypass, L2-hit). R5 PMC showed UC loads = HBM traffic (FETCH 1.7GB
// ~= UC read volume): L3 does not cache them -> ~900cy stalls. L2-local fixes it.
__device__ __forceinline__ float2 ld2m(const float* p, bool uc) {
  if (uc) return ld2(p);
  float2 v;
  asm volatile("global_load_dwordx2 %0, %1, off sc0\n\ts_waitcnt vmcnt(0)"
               : "=v"(v) : "v"(p) : "memory");
  return v;
}
__device__ __forceinline__ float ld1m(const float* p, bool uc) {
  if (uc) return ld1(p);
  float v;
  asm volatile("global_load_dword %0, %1, off sc0\n\ts_waitcnt vmcnt(0)"
               : "=v"(v) : "v"(p) : "memory");
  return v;
}
__device__ __forceinline__ void st1m(float* p, float v, bool uc) {
  if (uc) st1(p, v); else *p = v;
}
__device__ __forceinline__ void sthm(__half* p, __half v, bool uc) {
  if (uc) sth(p, v); else *p = v;
}

// ---- flag sync: no fences; data at its coherence point before arrive ----
__device__ __forceinline__ void poll(int* f, int tgt) {
  while (aLd(f) < tgt) __builtin_amdgcn_s_sleep(1);
}
__device__ __forceinline__ void flag_arrive(int* f) {
  asm volatile("s_waitcnt vmcnt(0)" ::: "memory");  // stores acked (L2/L3)
  __syncthreads();
  if (threadIdx.x == 0) aAdd(f, 1);
}
__device__ __forceinline__ void flag_wait3(int* f0, int t0, int* f1, int t1, int* f2, int t2) {
  if (threadIdx.x == 0 && f0) poll(f0, t0);
  if (threadIdx.x == 64 && f1) poll(f1, t1);
  if (threadIdx.x == 128 && f2) poll(f2, t2);
  __syncthreads();
}

// ---- LDS ----
struct SMT {
  union {
    struct { float Ws[32][132]; float Hs[32][36]; } a;   // 32rows x 128gc tiles
    struct { float Ws[32][68];  float Hs[32][68]; } b;   // 64rows x 64gc tiles
    struct { float As[32][65];  float Bs[32][65]; } g;   // enc_proj gemm
    struct { float h1s[256], qs[256], vs[256], sc[192], ctxs[512], sred[4]; } at;
  };
};

// ---- staging (W via plain cached loads; H via mode-aware transport) ----
__device__ __forceinline__ void stage_W128(const float* wTk, int gc0, float Ws[32][132]) {
  const int tid = threadIdx.x, gcq = tid & 31, kk4 = tid >> 5;
#pragma unroll
  for (int i = 0; i < 4; i++) {
    const int kk = kk4 * 4 + i;
    *(float4*)&Ws[kk][gcq * 4] = *(const float4*)(wTk + (ull)kk * 1024 + gc0 + gcq * 4);
  }
}
__device__ __forceinline__ void stage_W128h(const float* wTk, int gc0, float Ws[32][132]) { // 16 kk
  const int tid = threadIdx.x, gcq = tid & 31, kk2 = tid >> 5;
#pragma unroll
  for (int i = 0; i < 2; i++) {
    const int kk = kk2 * 2 + i;
    *(float4*)&Ws[kk][gcq * 4] = *(const float4*)(wTk + (ull)kk * 1024 + gc0 + gcq * 4);
  }
}
__device__ __forceinline__ void stage_W64(const float* wTk, int gc0, float Ws[32][68]) {
  const int tid = threadIdx.x, gcq = tid & 15, kk2 = tid >> 4;
#pragma unroll
  for (int i = 0; i < 2; i++) {
    const int kk = kk2 * 2 + i;
    *(float4*)&Ws[kk][gcq * 4] = *(const float4*)(wTk + (ull)kk * 1024 + gc0 + gcq * 4);
  }
}
__device__ __forceinline__ void stage_H32m(const float* h, ull rstride, int row0, int k0,
                                           int zero, bool uc, float Hs[32][36]) {
  const int tid = threadIdx.x, r = tid & 31, p = tid >> 5;
  if (zero) {
    Hs[p * 2][r] = 0.f; Hs[p * 2 + 1][r] = 0.f;
    Hs[(p + 8) * 2][r] = 0.f; Hs[(p + 8) * 2 + 1][r] = 0.f;
    return;
  }
  const float* q0 = h + (ull)(row0 + r) * rstride + k0 + p * 2;
  float2 a, b;
  if (uc) { a = ld2(q0); b = ld2(q0 + 16); }
  else {
    asm volatile("global_load_dwordx2 %0, %2, off sc0\n\t"
                 "global_load_dwordx2 %1, %3, off sc0\n\t"
                 "s_waitcnt vmcnt(0)"
                 : "=&v"(a), "=&v"(b) : "v"(q0), "v"(q0 + 16) : "memory");
  }
  Hs[p * 2][r] = a.x; Hs[p * 2 + 1][r] = a.y;
  Hs[(p + 8) * 2][r] = b.x; Hs[(p + 8) * 2 + 1][r] = b.y;
}
__device__ __forceinline__ void stage_H64m(const float* h, int row0, int k0,
                                           int zero, bool uc, float Hs[32][68]) {
  const int tid = threadIdx.x, r = tid & 63, p = tid >> 6;
  if (zero) {
#pragma unroll
    for (int j = 0; j < 4; j++) { Hs[(p + j * 4) * 2][r] = 0.f; Hs[(p + j * 4) * 2 + 1][r] = 0.f; }
    return;
  }
  const float* q0 = h + (ull)(row0 + r) * 256 + k0 + p * 2;
  float2 a, b, c, d;
  if (uc) { a = ld2(q0); b = ld2(q0 + 8); c = ld2(q0 + 16); d = ld2(q0 + 24); }
  else {
    asm volatile("global_load_dwordx2 %0, %4, off sc0\n\t"
                 "global_load_dwordx2 %1, %5, off sc0\n\t"
                 "global_load_dwordx2 %2, %6, off sc0\n\t"
                 "global_load_dwordx2 %3, %7, off sc0\n\t"
                 "s_waitcnt vmcnt(0)"
                 : "=&v"(a), "=&v"(b), "=&v"(c), "=&v"(d)
                 : "v"(q0), "v"(q0 + 8), "v"(q0 + 16), "v"(q0 + 24) : "memory");
  }
  Hs[p * 2][r] = a.x;            Hs[p * 2 + 1][r] = a.y;
  Hs[(p + 4) * 2][r] = b.x;      Hs[(p + 4) * 2 + 1][r] = b.y;
  Hs[(p + 8) * 2][r] = c.x;      Hs[(p + 8) * 2 + 1][r] = c.y;
  Hs[(p + 12) * 2][r] = d.x;     Hs[(p + 12) * 2 + 1][r] = d.y;
}

__device__ __forceinline__ void fma16(float acc[4][4], const float4 hv, const float4 wv) {
  acc[0][0] += hv.x * wv.x; acc[0][1] += hv.x * wv.y; acc[0][2] += hv.x * wv.z; acc[0][3] += hv.x * wv.w;
  acc[1][0] += hv.y * wv.x; acc[1][1] += hv.y * wv.y; acc[1][2] += hv.y * wv.z; acc[1][3] += hv.y * wv.w;
  acc[2][0] += hv.z * wv.x; acc[2][1] += hv.z * wv.y; acc[2][2] += hv.z * wv.z; acc[2][3] += hv.z * wv.w;
  acc[3][0] += hv.w * wv.x; acc[3][1] += hv.w * wv.y; acc[3][2] += hv.w * wv.z; acc[3][3] += hv.w * wv.w;
}
__device__ __forceinline__ void comp128(float Ws[32][132], float Hs[32][36], int bq, int ul,
                                        float acc[4][4], int nkk) {
#pragma unroll 8
  for (int kk = 0; kk < nkk; kk++)
    fma16(acc, *(const float4*)&Hs[kk][bq * 4], *(const float4*)&Ws[kk][ul * 4]);
}
__device__ __forceinline__ void comp64(float Ws[32][68], float Hs[32][68], int rq, int ul,
                                       float acc[4][4]) {
#pragma unroll 8
  for (int kk = 0; kk < 32; kk++)
    fma16(acc, *(const float4*)&Hs[kk][rq * 4], *(const float4*)&Ws[kk][ul * 4]);
}

// ---- attention + fc for one batch row ----
__device__ void attn_fc(int row, int t, int slot, const float* h1r, const float* wdT,
                        const float* attn_b, const float* attn_v,
                        const __half* P16, const __half* E16,
                        const float* fc_w, const float* fc_b,
                        float* ctxb, float* out, SMT& sm, bool uc)
{
  const int tid = threadIdx.x;
  __syncthreads();
  if (tid < 128) {
    float2 v = ld2m(h1r + (ull)slot * BH + (ull)row * 256 + tid * 2, uc);
    sm.at.h1s[tid * 2] = v.x; sm.at.h1s[tid * 2 + 1] = v.y;
  }
  __syncthreads();
  if (t >= 1 && tid < 64) {
    float a = 0.f;
#pragma unroll
    for (int j = 0; j < 4; j++) a += sm.at.h1s[tid + 64 * j] * fc_w[tid + 64 * j];
#pragma unroll
    for (int m = 32; m >= 1; m >>= 1) a += __shfl_xor(a, m, 64);
    if (tid == 0) {
      const float p = a + fc_b[0];
      out[(ull)row * TT + (t - 1)] = p;
      st1m(ctxb + (ull)row * 288 + 256, p, uc);
    }
  }
  if (t >= TT) return;
  float qv = attn_b[tid];
  for (int k = 0; k < 256; k += 4) {
    qv += sm.at.h1s[k]     * wdT[(ull)(k)     * 256 + tid];
    qv += sm.at.h1s[k + 1] * wdT[(ull)(k + 1) * 256 + tid];
    qv += sm.at.h1s[k + 2] * wdT[(ull)(k + 2) * 256 + tid];
    qv += sm.at.h1s[k + 3] * wdT[(ull)(k + 3) * 256 + tid];
  }
  sm.at.qs[tid] = qv;
  sm.at.vs[tid] = attn_v[tid];
  __syncthreads();
  const int wv = tid >> 6, lane = tid & 63;
  for (int s = wv; s < SS; s += 4) {
    const __half2* Pr = (const __half2*)(P16 + ((ull)row * SS + s) * 256);
    float a = 0.f;
#pragma unroll
    for (int jj = 0; jj < 2; jj++) {
      const int i2 = lane + 64 * jj;
      const float2 pv = __half22float2(Pr[i2]);
      const int g0 = i2 * 2;
      a += sm.at.vs[g0] * tanhf(pv.x + sm.at.qs[g0]);
      a += sm.at.vs[g0 + 1] * tanhf(pv.y + sm.at.qs[g0 + 1]);
    }
#pragma unroll
    for (int m = 32; m >= 1; m >>= 1) a += __shfl_xor(a, m, 64);
    if (lane == 0) sm.at.sc[s] = a;
  }
  __syncthreads();
  if (tid < 64) {
    float m = -1e30f;
    for (int i = tid; i < SS; i += 64) m = fmaxf(m, sm.at.sc[i]);
#pragma unroll
    for (int mm = 32; mm >= 1; mm >>= 1) m = fmaxf(m, __shfl_xor(m, mm, 64));
    if (tid == 0) sm.at.sred[0] = m;
  }
  __syncthreads();
  const float smax = sm.at.sred[0];
  if (tid < SS) sm.at.sc[tid] = expf(sm.at.sc[tid] - smax);
  __syncthreads();
  if (tid < 64) {
    float ssum = 0.f;
    for (int i = tid; i < SS; i += 64) ssum += sm.at.sc[i];
#pragma unroll
    for (int mm = 32; mm >= 1; mm >>= 1) ssum += __shfl_xor(ssum, mm, 64);
    if (tid == 0) sm.at.sred[1] = ssum;
  }
  __syncthreads();
  const float rinv = 1.f / sm.at.sred[1];
  const int u2 = tid & 127, sh = tid >> 7;
  float cx = 0.f, cy = 0.f;
  for (int s = sh * 84; s < sh * 84 + 84; s++) {
    const float w = sm.at.sc[s] * rinv;
    const float2 ev = __half22float2(*(const __half2*)(E16 + ((ull)row * SS + s) * 256 + u2 * 2));
    cx += w * ev.x; cy += w * ev.y;
  }
  sm.at.ctxs[sh * 256 + u2 * 2] = cx;
  sm.at.ctxs[sh * 256 + u2 * 2 + 1] = cy;
  __syncthreads();
  st1m(ctxb + (ull)row * 288 + tid, sm.at.ctxs[tid] + sm.at.ctxs[256 + tid], uc);
}

// ---- enc_proj 64x64 gemm tile: P16 = E16 @ We^T (group-local rows) ----
__device__ void proj_tile(const __half* E16, const float* attn_w, __half* P16,
                          int m0, int n0, SMT& sm)
{
  const int tid = threadIdx.x;
  const int mq = tid & 15, nq = tid >> 4;
  const int li = tid & 63, kq = tid >> 6;
  float acc[4][4] = {{0.f}};
  for (int k0 = 0; k0 < 256; k0 += 32) {
    float4 raw = *(const float4*)(E16 + (ull)(m0 + li) * 256 + k0 + kq * 8);
    const __half* hp = (const __half*)&raw;
#pragma unroll
    for (int i = 0; i < 8; i++) sm.g.As[kq * 8 + i][li] = __half2float(hp[i]);
    const float* gb = attn_w + (ull)(n0 + li) * 512 + k0 + kq * 8;
    const float4 v0 = *(const float4*)gb, v1 = *(const float4*)(gb + 4);
    sm.g.Bs[kq * 8 + 0][li] = v0.x; sm.g.Bs[kq * 8 + 1][li] = v0.y;
    sm.g.Bs[kq * 8 + 2][li] = v0.z; sm.g.Bs[kq * 8 + 3][li] = v0.w;
    sm.g.Bs[kq * 8 + 4][li] = v1.x; sm.g.Bs[kq * 8 + 5][li] = v1.y;
    sm.g.Bs[kq * 8 + 6][li] = v1.z; sm.g.Bs[kq * 8 + 7][li] = v1.w;
    __syncthreads();
#pragma unroll 8
    for (int kk = 0; kk < 32; kk++) {
      const float4 a4 = *(const float4*)&sm.g.As[kk][mq * 4];
      const float4 b4 = *(const float4*)&sm.g.Bs[kk][nq * 4];
      fma16(acc, a4, b4);
    }
    __syncthreads();
  }
#pragma unroll
  for (int i = 0; i < 4; i++) {
    const int m = m0 + mq * 4 + i;
#pragma unroll
    for (int j = 0; j < 2; j++) {
      __half2 h2; h2.x = __float2half(acc[i][j * 2]); h2.y = __float2half(acc[i][j * 2 + 1]);
      *(__half2*)(P16 + (ull)m * 256 + n0 + nq * 4 + j * 2) = h2;
    }
  }
}

// ---------------------------------------------------------------------------
__global__ __launch_bounds__(256, 1) void seq2seq_pipe(
    const float* __restrict__ src,
    const float* __restrict__ attn_w, const float* __restrict__ attn_b,
    const float* __restrict__ attn_v,
    const float* __restrict__ fc_w, const float* __restrict__ fc_b,
    float* __restrict__ out, int* __restrict__ ib)
{
  __shared__ SMT sm;
  __shared__ int sh2[2];
  const int tid = threadIdx.x;
  float* fb = (float*)ib + 65536;
  float* y0r  = fb + O_Y0;
  float* h1r  = fb + O_H1;
  float* h0r  = fb + O_H0;
  float* ctxb = fb + O_CTX;
  const float* wT0 = fb + O_WT0;
  const float* wT1 = fb + O_WT1;
  const float* wD0 = fb + O_WD0;
  const float* wD1 = fb + O_WD1;
  const float* wdT = fb + O_WDT;
  const float* bp  = fb + O_BP;
  __half* E16 = (__half*)(fb + O_E16);
  __half* P16 = (__half*)(fb + O_P16);

  // ==== runtime role assignment by physical XCD (G16-safe: any mapping ok) ====
  if (tid == 0) {
    int xcd;
    asm volatile("s_getreg_b32 %0, hwreg(HW_REG_XCC_ID)" : "=s"(xcd));
    xcd &= 7;
    int* cnt = ib + 8192; int* rcnt = ib + 8200; int* rdone = ib + 8201;
    int* scnt = ib + 8202; int* sdone = ib + 8203; int* smask = ib + 8204;
    int* sidx = ib + 8205; int* clm = ib + 8208;
    int role = -1, spill = 0;
    int r = aAdd(cnt + xcd, 1);
    if (r < 32) { role = xcd * 32 + r; aSt(clm + role, 1); }
    else { spill = 1; aAdd(scnt, 1); }
    asm volatile("s_waitcnt vmcnt(0)" ::: "memory");  // claims/scnt at L3 first
    if (aAdd(rcnt, 1) == 255) aSt(rdone, 1);
    else while (!aLd(rdone)) __builtin_amdgcn_s_sleep(1);
    if (spill) {
      int idx = aAdd(sidx, 1), seen = -1;
      for (int rr = 0; rr < 256 && role < 0; rr++)
        if (!aLd(clm + rr)) { if (++seen == idx) role = rr; }
      aOr(smask, 1 << (role >> 5));
      asm volatile("s_waitcnt vmcnt(0)" ::: "memory");
      aAdd(sdone, 1);
    }
    int ts = aLd(scnt);
    while (aLd(sdone) < ts) __builtin_amdgcn_s_sleep(1);
    sh2[0] = role;
    sh2[1] = (aLd(smask) >> (role >> 5)) & 1;  // group has cross-XCD member -> UC mode
  }
  __syncthreads();
  const int role = sh2[0];
  const bool uc = (sh2[1] != 0);
  const int g = role >> 5, m = role & 31;
  const int rowg = g * 64;
  int* gf = ib + g * 1024;

  float cReg[4] = {0.f, 0.f, 0.f, 0.f};

  if (m < 16) {
    // ==== encoder layer 0: 2 row-halves x 8 u-slices (group rows rowg..+63) ====
    const int bt0l = m & 1, ut0 = m >> 1;
    const int row0 = rowg + bt0l * 32, gc0 = ut0 * 128;
    const int bq = tid & 7, ul = tid >> 3;
    const int u = ut0 * 32 + ul;
    const float4 bv = *(const float4*)(bp + gc0 + ul * 4);
    for (int t = 0; t < SS; t++) {
      flag_wait3(t ? gf + (t - 1) * 2 + bt0l : nullptr, 8,
                 t >= 4 ? gf + 512 + (t - 4) : nullptr, 16, nullptr, 0);
      float acc[4][4];
#pragma unroll
      for (int bd = 0; bd < 4; bd++) { acc[bd][0] = bv.x; acc[bd][1] = bv.y; acc[bd][2] = bv.z; acc[bd][3] = bv.w; }
      {
        const int r = tid & 31, f = tid >> 5;
        sm.a.Hs[f][r]     = src[((ull)(row0 + r) * SS + t) * 16 + f];
        sm.a.Hs[f + 8][r] = src[((ull)(row0 + r) * SS + t) * 16 + f + 8];
      }
      stage_W128h(wT0, gc0, sm.a.Ws);
      __syncthreads();
      comp128(sm.a.Ws, sm.a.Hs, bq, ul, acc, 16);
      __syncthreads();
      const float* hsrc = y0r + (ull)((t + 3) & 3) * BH;
      for (int c8 = 0; c8 < 8; c8++) {
        stage_W128(wT0 + (ull)(16 + c8 * 32) * 1024, gc0, sm.a.Ws);
        stage_H32m(hsrc, 256, row0, c8 * 32, t == 0, uc, sm.a.Hs);
        __syncthreads();
        comp128(sm.a.Ws, sm.a.Hs, bq, ul, acc, 32);
        __syncthreads();
      }
      float* yo = y0r + (ull)(t & 3) * BH;
#pragma unroll
      for (int bd = 0; bd < 4; bd++) {
        const int row = row0 + bq * 4 + bd;
        const float iv = sigf(acc[bd][0]), fv = sigf(acc[bd][1]);
        const float gv = tanhf(acc[bd][2]), ov = sigf(acc[bd][3]);
        const float cn = fv * cReg[bd] + iv * gv;
        cReg[bd] = cn;
        st1m(yo + (ull)row * 256 + u, ov * tanhf(cn), uc);
      }
      flag_arrive(gf + t * 2 + bt0l);
    }
  } else {
    // ==== encoder layer 1: 16 u-slices, all 64 group rows ====
    const int ut1 = m - 16;
    const int row0 = rowg, gc0 = ut1 * 64;
    const int rq = tid & 15, ul = tid >> 4;
    const int u = ut1 * 16 + ul;
    const float4 bv = *(const float4*)(bp + 1024 + gc0 + ul * 4);
    for (int s = 0; s < SS; s++) {
      flag_wait3(gf + s * 2 + 0, 8, gf + s * 2 + 1, 8,
                 s ? gf + 512 + (s - 1) : nullptr, 16);
      float acc[4][4];
#pragma unroll
      for (int bd = 0; bd < 4; bd++) { acc[bd][0] = bv.x; acc[bd][1] = bv.y; acc[bd][2] = bv.z; acc[bd][3] = bv.w; }
      const float* ysrc = y0r + (ull)(s & 3) * BH;
      const float* hsrc = h1r + (ull)((s + 1) & 1) * BH;
      for (int c8 = 0; c8 < 16; c8++) {
        stage_W64(wT1 + (ull)(c8 * 32) * 1024, gc0, sm.b.Ws);
        if (c8 < 8) stage_H64m(ysrc, row0, c8 * 32, 0, uc, sm.b.Hs);
        else        stage_H64m(hsrc, row0, (c8 - 8) * 32, s == 0, uc, sm.b.Hs);
        __syncthreads();
        comp64(sm.b.Ws, sm.b.Hs, rq, ul, acc);
        __syncthreads();
      }
      float* ho = h1r + (ull)(s & 1) * BH;
#pragma unroll
      for (int bd = 0; bd < 4; bd++) {
        const int row = row0 + rq * 4 + bd;
        const float iv = sigf(acc[bd][0]), fv = sigf(acc[bd][1]);
        const float gv = tanhf(acc[bd][2]), ov = sigf(acc[bd][3]);
        const float cn = fv * cReg[bd] + iv * gv;
        cReg[bd] = cn;
        const float hn = ov * tanhf(cn);
        st1m(ho + (ull)row * 256 + u, hn, uc);
        sthm(E16 + ((ull)row * SS + s) * 256 + u, __float2half(hn), uc);
      }
      flag_arrive(gf + 512 + s);
    }
  }

  // ==== enc_proj: group-local rows, 21 tiles per block ====
  if (tid == 0) poll(gf + 512 + 167, 16);
  __syncthreads();
  {
    const int em0 = rowg * SS;  // group's base M row in E16-matrix view
    for (int tau = m; tau < 672; tau += 32)
      proj_tile(E16, attn_w, P16, em0 + (tau >> 2) * 64, (tau & 3) * 64, sm);
  }
  flag_arrive(gf + 900);

  // ==== decoder (cReg NOT reset: cell0/cell1 inherit enc-final c0e/c1e,
  //      identical (row,u) partition per role) ====
  for (int t = 0; t <= TT; t++) {
    if (t == 0) flag_wait3(gf + 900, 32, nullptr, 0, nullptr, 0);
    else flag_wait3(gf + 768 + (t - 1), 16, nullptr, 0, nullptr, 0);
    const int slot = (t + 1) & 1;
    attn_fc(rowg + 2 * m,     t, slot, h1r, wdT, attn_b, attn_v, P16, E16, fc_w, fc_b, ctxb, out, sm, uc);
    attn_fc(rowg + 2 * m + 1, t, slot, h1r, wdT, attn_b, attn_v, P16, E16, fc_w, fc_b, ctxb, out, sm, uc);
    if (t == TT) break;
    flag_arrive(gf + 704 + t);
    if (m < 16) {
      // ---- dec cell0: x = [ctx(256) | h0prev(256) | pred(1)] ----
      const int bt0l = m & 1, ut0 = m >> 1;
      const int row0 = rowg + bt0l * 32, gc0 = ut0 * 128;
      const int bq = tid & 7, ul = tid >> 3;
      const int u = ut0 * 32 + ul;
      flag_wait3(gf + 704 + t, 32, t ? gf + 736 + (t - 1) : nullptr, 16, nullptr, 0);
      const float4 bv = *(const float4*)(bp + 2048 + gc0 + ul * 4);
      float acc[4][4];
#pragma unroll
      for (int bd = 0; bd < 4; bd++) { acc[bd][0] = bv.x; acc[bd][1] = bv.y; acc[bd][2] = bv.z; acc[bd][3] = bv.w; }
      const float* h0src = (t == 0) ? y0r + 3 * BH : h0r + (ull)((t + 1) & 1) * BH;
      for (int c8 = 0; c8 < 16; c8++) {
        stage_W128(wD0 + (ull)(c8 * 32) * 1024, gc0, sm.a.Ws);
        if (c8 < 8) stage_H32m(ctxb, 288, row0, c8 * 32, 0, uc, sm.a.Hs);
        else        stage_H32m(h0src, 256, row0, (c8 - 8) * 32, 0, uc, sm.a.Hs);
        __syncthreads();
        comp128(sm.a.Ws, sm.a.Hs, bq, ul, acc, 32);
        __syncthreads();
      }
      const float4 wp = *(const float4*)(wD0 + 512ull * 1024 + gc0 + ul * 4);
      float* ho = h0r + (ull)(t & 1) * BH;
#pragma unroll
      for (int bd = 0; bd < 4; bd++) {
        const int row = row0 + bq * 4 + bd;
        const float p = ld1m(ctxb + (ull)row * 288 + 256, uc);
        acc[bd][0] += p * wp.x; acc[bd][1] += p * wp.y; acc[bd][2] += p * wp.z; acc[bd][3] += p * wp.w;
        const float iv = sigf(acc[bd][0]), fv = sigf(acc[bd][1]);
        const float gv = tanhf(acc[bd][2]), ov = sigf(acc[bd][3]);
        const float cn = fv * cReg[bd] + iv * gv;
        cReg[bd] = cn;
        st1m(ho + (ull)row * 256 + u, ov * tanhf(cn), uc);
      }
      flag_arrive(gf + 736 + t);
    } else {
      // ---- dec cell1: x = [h0new(256) | h1prev(256)] ----
      const int ut1 = m - 16;
      const int row0 = rowg, gc0 = ut1 * 64;
      const int rq = tid & 15, ul = tid >> 4;
      const int u = ut1 * 16 + ul;
      flag_wait3(gf + 736 + t, 16, t ? gf + 768 + (t - 1) : nullptr, 16, nullptr, 0);
      const float4 bv = *(const float4*)(bp + 3072 + gc0 + ul * 4);
      float acc[4][4];
#pragma unroll
      for (int bd = 0; bd < 4; bd++) { acc[bd][0] = bv.x; acc[bd][1] = bv.y; acc[bd][2] = bv.z; acc[bd][3] = bv.w; }
      const float* h0src = h0r + (ull)(t & 1) * BH;
      const float* h1src = h1r + (ull)((t + 1) & 1) * BH;
      for (int c8 = 0; c8 < 16; c8++) {
        stage_W64(wD1 + (ull)(c8 * 32) * 1024, gc0, sm.b.Ws);
        if (c8 < 8) stage_H64m(h0src, row0, c8 * 32, 0, uc, sm.b.Hs);
        else        stage_H64m(h1src, row0, (c8 - 8) * 32, 0, uc, sm.b.Hs);
        __syncthreads();
        comp64(sm.b.Ws, sm.b.Hs, rq, ul, acc);
        __syncthreads();
      }
      float* ho = h1r + (ull)(t & 1) * BH;
#pragma unroll
      for (int bd = 0; bd < 4; bd++) {
        const int row = row0 + rq * 4 + bd;
        const float iv = sigf(acc[bd][0]), fv = sigf(acc[bd][1]);
        const float gv = tanhf(acc[bd][2]), ov = sigf(acc[bd][3]);
        const float cn = fv * cReg[bd] + iv * gv;
        cReg[bd] = cn;
        st1m(ho + (ull)row * 256 + u, ov * tanhf(cn), uc);
      }
      flag_arrive(gf + 768 + t);
    }
  }
}

// ---------------------------------------------------------------------------
// Init kernel: zero flags+control, pre-transpose weights (col = u*4+gate),
// pack biases, seed ctx pred col with dec_in0.
// ---------------------------------------------------------------------------
__global__ void init_all(
    const float* __restrict__ src,
    const float* __restrict__ ewih0, const float* __restrict__ ewhh0, const float* __restrict__ eb0,
    const float* __restrict__ ewih1, const float* __restrict__ ewhh1, const float* __restrict__ eb1,
    const float* __restrict__ dwih0, const float* __restrict__ dwhh0, const float* __restrict__ db0,
    const float* __restrict__ dwih1, const float* __restrict__ dwhh1, const float* __restrict__ db1,
    const float* __restrict__ attn_w, int* __restrict__ ib)
{
  const int gid = blockIdx.x * 256 + threadIdx.x;
  const int NG = 1024 * 256;
  float* fb = (float*)ib + 65536;
  for (int i = gid; i < 8464; i += NG) ib[i] = 0;
  for (int i = gid; i < 272 * 1024; i += NG) {
    const int k = i >> 10, cg = i & 1023, j = (cg & 3) * 256 + (cg >> 2);
    fb[O_WT0 + i] = (k < 16) ? ewih0[(ull)j * 16 + k] : ewhh0[(ull)j * 256 + k - 16];
  }
  for (int i = gid; i < 512 * 1024; i += NG) {
    const int k = i >> 10, cg = i & 1023, j = (cg & 3) * 256 + (cg >> 2);
    fb[O_WT1 + i] = (k < 256) ? ewih1[(ull)j * 256 + k] : ewhh1[(ull)j * 256 + k - 256];
  }
  for (int i = gid; i < 513 * 1024; i += NG) {
    const int k = i >> 10, cg = i & 1023, j = (cg & 3) * 256 + (cg >> 2);
    float v;
    if (k < 256) v = dwih0[(ull)j * 257 + 1 + k];
    else if (k < 512) v = dwhh0[(ull)j * 256 + k - 256];
    else v = dwih0[(ull)j * 257];
    fb[O_WD0 + i] = v;
  }
  for (int i = gid; i < 512 * 1024; i += NG) {
    const int k = i >> 10, cg = i & 1023, j = (cg & 3) * 256 + (cg >> 2);
    fb[O_WD1 + i] = (k < 256) ? dwih1[(ull)j * 256 + k] : dwhh1[(ull)j * 256 + k - 256];
  }
  for (int i = gid; i < 256 * 256; i += NG) {
    const int k = i >> 8, gg = i & 255;
    fb[O_WDT + i] = attn_w[(ull)gg * 512 + 256 + k];
  }
  for (int i = gid; i < 4096; i += NG) {
    const int set = i >> 10, cg = i & 1023, j = (cg & 3) * 256 + (cg >> 2);
    const float* bsrc = (set == 0) ? eb0 : (set == 1) ? eb1 : (set == 2) ? db0 : db1;
    fb[O_BP + i] = bsrc[j];
  }
  for (int i = gid; i < 512; i += NG)
    fb[O_CTX + (ull)i * 288 + 256] = src[((ull)i * SS + 167) * 16 + 15];
}

extern "C" void kernel_launch(void* const* d_in, const int* in_sizes, int n_in,
                              void* d_out, int out_size, void* d_ws, size_t ws_size,
                              hipStream_t stream)
{
  const float* src    = (const float*)d_in[0];
  const float* ewih0  = (const float*)d_in[1];
  const float* ewhh0  = (const float*)d_in[2];
  const float* eb0    = (const float*)d_in[3];
  const float* ewih1  = (const float*)d_in[4];
  const float* ewhh1  = (const float*)d_in[5];
  const float* eb1    = (const float*)d_in[6];
  const float* dwih0  = (const float*)d_in[7];
  const float* dwhh0  = (const float*)d_in[8];
  const float* db0    = (const float*)d_in[9];
  const float* dwih1  = (const float*)d_in[10];
  const float* dwhh1  = (const float*)d_in[11];
  const float* db1    = (const float*)d_in[12];
  const float* attn_w = (const float*)d_in[13];
  const float* attn_b = (const float*)d_in[14];
  const float* attn_v = (const float*)d_in[15];
  // d_in[16] pos_bias: post-tanh, uniform over s -> softmax-invariant, unused.
  const float* fc_w   = (const float*)d_in[17];
  const float* fc_b   = (const float*)d_in[18];
  float* out = (float*)d_out;
  int* ib    = (int*)d_ws;

  init_all<<<1024, 256, 0, stream>>>(src, ewih0, ewhh0, eb0, ewih1, ewhh1, eb1,
                                     dwih0, dwhh0, db0, dwih1, dwhh1, db1, attn_w, ib);

  void* args[] = {
    (void*)&src, (void*)&attn_w, (void*)&attn_b, (void*)&attn_v,
    (void*)&fc_w, (void*)&fc_b, (void*)&out, (void*)&ib,
  };
  hipLaunchCooperativeKernel((const void*)seq2seq_pipe, dim3(NBLK), dim3(NTHR),
                             args, 0, stream);
}

// Round 7
// 10289.312 us; speedup vs baseline: 1.2309x; 1.2309x over previous
//
#include <hip/hip_runtime.h>
#include <hip/hip_fp16.h>
#include <math.h>

#define BB 512
#define HH 256
#define SS 168
#define TT 24
#define NBLK 256
#define NTHR 256
typedef unsigned long long ull;
#define BH 131072ull  // 512*256

// ---- int area (from ws): per-group flags at ib + g*1024 ----
//   ife[0..168] tgt 32 | ifa 704+t tgt 32 | ifh0 736+t tgt 16 | ifh1 768+t tgt 16 | ifp 900 tgt 32
// ---- float offsets from fb = (float*)ws + 65536 ----
#define O_Y0  0ull        // y0 ring (2 slots used of 4)
#define O_H1  524288ull   // h1 ring, 2 slots
#define O_H0  786432ull   // dec h0 ring, 2 slots; slot1 doubles as zb during encoder
#define O_CTX 1048576ull  // 512 x 288 (cols 0..255 ctx, col 256 pred)
#define O_WT0 1196032ull  // enc l0 W^T [272][1024]
#define O_WT1 1474560ull  // enc l1 W^T [512][1024]
#define O_WD0 1998848ull  // dec c0 W^T [513][1024]
#define O_WD1 2524160ull  // dec c1 W^T [512][1024]
#define O_WDT 3048448ull  // Wd^T [256][256]
#define O_BP  3113984ull  // packed biases 4x1024 (e0,e1,d0,d1)
#define O_E16 3118080ull  // half[512][168][256]
#define O_P16 14128128ull // half[512][168][256]

typedef float v2f __attribute__((ext_vector_type(2)));
typedef float v4f __attribute__((ext_vector_type(4)));

__device__ __forceinline__ float sigf(float x) { return 1.f / (1.f + expf(-x)); }

#define AR __ATOMIC_RELAXED
#define SCA __HIP_MEMORY_SCOPE_AGENT
__device__ __forceinline__ int aLd(int* p) { return __hip_atomic_load(p, AR, SCA); }
__device__ __forceinline__ int aAdd(int* p, int v) { return __hip_atomic_fetch_add(p, v, AR, SCA); }

// ---- UC transport: relaxed agent-scope (coherence-point) ops, no fences ----
__device__ __forceinline__ float2 ld2(const float* p) {
  ull raw = __hip_atomic_load((const ull*)p, AR, SCA);
  float2 v; v.x = __uint_as_float((unsigned)raw); v.y = __uint_as_float((unsigned)(raw >> 32));
  return v;
}
__device__ __forceinline__ float ld1(const float* p) {
  unsigned raw = __hip_atomic_load((const unsigned*)p, AR, SCA);
  return __uint_as_float(raw);
}
__device__ __forceinline__ void st1(float* p, float v) {
  __hip_atomic_store((unsigned*)p, __float_as_uint(v), AR, SCA);
}
__device__ __forceinline__ void sth(__half* p, __half v) {
  __hip_atomic_store((unsigned short*)p, __half_as_ushort(v), AR, SCA);
}
__device__ __forceinline__ void stu(unsigned* p, unsigned v) {
  __hip_atomic_store(p, v, AR, SCA);
}

// ---- manual-vmcnt loads (keep compiler vmem out of the pipelined loop) ----
__device__ __forceinline__ void ld_h(const float* p, v2f& a, v2f& b) {
  asm volatile("global_load_dwordx2 %0, %2, off sc0 sc1\n\t"
               "global_load_dwordx2 %1, %3, off sc0 sc1"
               : "=&v"(a), "=&v"(b) : "v"(p), "v"(p + 16) : "memory");
}
struct W4 { v4f v[4]; };
__device__ __forceinline__ void ld_w(const float* p, W4& w) {
  asm volatile("global_load_dwordx4 %0, %4, off\n\t"
               "global_load_dwordx4 %1, %5, off\n\t"
               "global_load_dwordx4 %2, %6, off\n\t"
               "global_load_dwordx4 %3, %7, off"
               : "=&v"(w.v[0]), "=&v"(w.v[1]), "=&v"(w.v[2]), "=&v"(w.v[3])
               : "v"(p), "v"(p + 1024), "v"(p + 2048), "v"(p + 3072) : "memory");
}
#define VMW(n) asm volatile("s_waitcnt vmcnt(" #n ")" ::: "memory")

// ---- flag sync: no fences; data at coherence point before arrive ----
__device__ __forceinline__ void poll(int* f, int tgt) {
  while (aLd(f) < tgt) __builtin_amdgcn_s_sleep(1);
}
__device__ __forceinline__ void flag_arrive(int* f) {
  asm volatile("s_waitcnt vmcnt(0)" ::: "memory");
  __syncthreads();
  if (threadIdx.x == 0) aAdd(f, 1);
}
__device__ __forceinline__ void flag_wait2(int* f0, int t0, int* f1, int t1) {
  if (threadIdx.x == 0 && f0) poll(f0, t0);
  if (threadIdx.x == 64 && f1) poll(f1, t1);
  __syncthreads();
}

// ---- LDS ----
struct SMT {
  union {
    struct { float Ws[32][132]; float Hs[32][36]; } a;   // 32r x 128gc tile
    struct { float As[32][65];  float Bs[32][65]; } g;   // enc_proj gemm
    struct { float h1s[256], qs[256], vs[256], sc[192], ctxs[512], sred[4]; } at;
  };
};

__device__ __forceinline__ void stage_W128h(const float* wTk, int gc0, float Ws[32][132]) { // 16 kk
  const int tid = threadIdx.x, gcq = tid & 31, kk2 = tid >> 5;
#pragma unroll
  for (int i = 0; i < 2; i++) {
    const int kk = kk2 * 2 + i;
    *(float4*)&Ws[kk][gcq * 4] = *(const float4*)(wTk + (ull)kk * 1024 + gc0 + gcq * 4);
  }
}

__device__ __forceinline__ void fma16(float acc[4][4], const float4 hv, const float4 wv) {
  acc[0][0] += hv.x * wv.x; acc[0][1] += hv.x * wv.y; acc[0][2] += hv.x * wv.z; acc[0][3] += hv.x * wv.w;
  acc[1][0] += hv.y * wv.x; acc[1][1] += hv.y * wv.y; acc[1][2] += hv.y * wv.z; acc[1][3] += hv.y * wv.w;
  acc[2][0] += hv.z * wv.x; acc[2][1] += hv.z * wv.y; acc[2][2] += hv.z * wv.z; acc[2][3] += hv.z * wv.w;
  acc[3][0] += hv.w * wv.x; acc[3][1] += hv.w * wv.y; acc[3][2] += hv.w * wv.z; acc[3][3] += hv.w * wv.w;
}
__device__ __forceinline__ void comp128(float Ws[32][132], float Hs[32][36], int bq, int ul,
                                        float acc[4][4], int nkk) {
#pragma unroll 8
  for (int kk = 0; kk < nkk; kk++)
    fma16(acc, *(const float4*)&Hs[kk][bq * 4], *(const float4*)&Ws[kk][ul * 4]);
}

// ---------------------------------------------------------------------------
// Software-pipelined gate-GEMM over NC 32-K chunks. W prefetched 1 chunk
// ahead (cached), H 1 ahead (UC sc0 sc1). vmcnt(6) = the 6 newest loads
// (4 W + 2 H of chunk c+1) may stay in flight while chunk c computes.
// hb0/hb1/wb are per-thread base pointers. Junk prefetch beyond NC stays
// inside ws (arrays are adjacent); drained by UCWAIT before reg reuse.
// ---------------------------------------------------------------------------
__device__ void gemm_pipe(const float* hb0, const float* hb1, const float* wb,
                          int NC, int nc0, float acc[4][4], SMT& sm)
{
  const int tid = threadIdx.x;
  const int r = tid & 31, p2 = tid >> 5;          // H staging coords
  const int gcq = tid & 31, kk4 = tid >> 5;       // W staging coords
  const int bq = tid & 7, ul = tid >> 3;          // compute coords
  v2f hA0, hA1, hB0, hB1;
  W4 wA, wB;
  const float* h1p = hb1 - (ull)nc0 * 32;
  ld_h(hb0, hA0, hA1);
  ld_w(wb, wA);
  for (int c = 0; c < NC; c += 2) {
    ld_w(wb + (ull)(c + 1) * 32768, wB);
    ld_h((c + 1 < nc0 ? hb0 + (c + 1) * 32 : h1p + (c + 1) * 32), hB0, hB1);
    VMW(6);
#pragma unroll
    for (int i = 0; i < 4; i++) *(v4f*)&sm.a.Ws[kk4 * 4 + i][gcq * 4] = wA.v[i];
    sm.a.Hs[p2 * 2][r] = hA0[0]; sm.a.Hs[p2 * 2 + 1][r] = hA0[1];
    sm.a.Hs[(p2 + 8) * 2][r] = hA1[0]; sm.a.Hs[(p2 + 8) * 2 + 1][r] = hA1[1];
    __syncthreads();
    comp128(sm.a.Ws, sm.a.Hs, bq, ul, acc, 32);
    __syncthreads();
    ld_w(wb + (ull)(c + 2) * 32768, wA);
    ld_h((c + 2 < nc0 ? hb0 + (c + 2) * 32 : h1p + (c + 2) * 32), hA0, hA1);
    VMW(6);
#pragma unroll
    for (int i = 0; i < 4; i++) *(v4f*)&sm.a.Ws[kk4 * 4 + i][gcq * 4] = wB.v[i];
    sm.a.Hs[p2 * 2][r] = hB0[0]; sm.a.Hs[p2 * 2 + 1][r] = hB0[1];
    sm.a.Hs[(p2 + 8) * 2][r] = hB1[0]; sm.a.Hs[(p2 + 8) * 2 + 1][r] = hB1[1];
    __syncthreads();
    comp128(sm.a.Ws, sm.a.Hs, bq, ul, acc, 32);
    __syncthreads();
  }
  asm volatile("s_waitcnt vmcnt(0)" ::: "memory");  // junk drained before reg reuse
}

__device__ __forceinline__ void lstm_epi(float acc[4][4], float cReg[4], int row0, int u,
                                         float* hout, __half* e16, int sstep)
{
  const int bq = threadIdx.x & 7;
#pragma unroll
  for (int bd = 0; bd < 4; bd++) {
    const int row = row0 + bq * 4 + bd;
    const float iv = sigf(acc[bd][0]), fv = sigf(acc[bd][1]);
    const float gv = tanhf(acc[bd][2]), ov = sigf(acc[bd][3]);
    const float cn = fv * cReg[bd] + iv * gv;
    cReg[bd] = cn;
    const float hn = ov * tanhf(cn);
    st1(hout + (ull)row * 256 + u, hn);
    if (e16) sth(e16 + ((ull)row * SS + sstep) * 256 + u, __float2half(hn));
  }
}

// ---- attention + fc for one batch row (UC transport) ----
__device__ void attn_fc(int row, int t, int slot, const float* h1r, const float* wdT,
                        const float* attn_b, const float* attn_v,
                        const __half* P16, const __half* E16,
                        const float* fc_w, const float* fc_b,
                        float* ctxb, float* out, SMT& sm)
{
  const int tid = threadIdx.x;
  __syncthreads();
  if (tid < 128) {
    float2 v = ld2(h1r + (ull)slot * BH + (ull)row * 256 + tid * 2);
    sm.at.h1s[tid * 2] = v.x; sm.at.h1s[tid * 2 + 1] = v.y;
  }
  __syncthreads();
  if (t >= 1 && tid < 64) {
    float a = 0.f;
#pragma unroll
    for (int j = 0; j < 4; j++) a += sm.at.h1s[tid + 64 * j] * fc_w[tid + 64 * j];
#pragma unroll
    for (int m = 32; m >= 1; m >>= 1) a += __shfl_xor(a, m, 64);
    if (tid == 0) {
      const float p = a + fc_b[0];
      out[(ull)row * TT + (t - 1)] = p;
      st1(ctxb + (ull)row * 288 + 256, p);
    }
  }
  if (t >= TT) return;
  float qv = attn_b[tid];
  for (int k = 0; k < 256; k += 4) {
    qv += sm.at.h1s[k]     * wdT[(ull)(k)     * 256 + tid];
    qv += sm.at.h1s[k + 1] * wdT[(ull)(k + 1) * 256 + tid];
    qv += sm.at.h1s[k + 2] * wdT[(ull)(k + 2) * 256 + tid];
    qv += sm.at.h1s[k + 3] * wdT[(ull)(k + 3) * 256 + tid];
  }
  sm.at.qs[tid] = qv;
  sm.at.vs[tid] = attn_v[tid];
  __syncthreads();
  const int wv = tid >> 6, lane = tid & 63;
  for (int s = wv; s < SS; s += 4) {
    const __half2* Pr = (const __half2*)(P16 + ((ull)row * SS + s) * 256);
    float a = 0.f;
#pragma unroll
    for (int jj = 0; jj < 2; jj++) {
      const int i2 = lane + 64 * jj;
      const float2 pv = __half22float2(Pr[i2]);
      const int g0 = i2 * 2;
      a += sm.at.vs[g0] * tanhf(pv.x + sm.at.qs[g0]);
      a += sm.at.vs[g0 + 1] * tanhf(pv.y + sm.at.qs[g0 + 1]);
    }
#pragma unroll
    for (int m = 32; m >= 1; m >>= 1) a += __shfl_xor(a, m, 64);
    if (lane == 0) sm.at.sc[s] = a;
  }
  __syncthreads();
  if (tid < 64) {
    float m = -1e30f;
    for (int i = tid; i < SS; i += 64) m = fmaxf(m, sm.at.sc[i]);
#pragma unroll
    for (int mm = 32; mm >= 1; mm >>= 1) m = fmaxf(m, __shfl_xor(m, mm, 64));
    if (tid == 0) sm.at.sred[0] = m;
  }
  __syncthreads();
  const float smax = sm.at.sred[0];
  if (tid < SS) sm.at.sc[tid] = expf(sm.at.sc[tid] - smax);
  __syncthreads();
  if (tid < 64) {
    float ssum = 0.f;
    for (int i = tid; i < SS; i += 64) ssum += sm.at.sc[i];
#pragma unroll
    for (int mm = 32; mm >= 1; mm >>= 1) ssum += __shfl_xor(ssum, mm, 64);
    if (tid == 0) sm.at.sred[1] = ssum;
  }
  __syncthreads();
  const float rinv = 1.f / sm.at.sred[1];
  const int u2 = tid & 127, sh = tid >> 7;
  float cx = 0.f, cy = 0.f;
  for (int s = sh * 84; s < sh * 84 + 84; s++) {
    const float w = sm.at.sc[s] * rinv;
    const float2 ev = __half22float2(*(const __half2*)(E16 + ((ull)row * SS + s) * 256 + u2 * 2));
    cx += w * ev.x; cy += w * ev.y;
  }
  sm.at.ctxs[sh * 256 + u2 * 2] = cx;
  sm.at.ctxs[sh * 256 + u2 * 2 + 1] = cy;
  __syncthreads();
  st1(ctxb + (ull)row * 288 + tid, sm.at.ctxs[tid] + sm.at.ctxs[256 + tid]);
}

// ---- enc_proj 64x64 gemm tile: P16 = E16 @ We^T; P16 stored UC ----
__device__ void proj_tile(const __half* E16, const float* attn_w, __half* P16,
                          int m0, int n0, SMT& sm)
{
  const int tid = threadIdx.x;
  const int mq = tid & 15, nq = tid >> 4;
  const int li = tid & 63, kq = tid >> 6;
  float acc[4][4] = {{0.f}};
  for (int k0 = 0; k0 < 256; k0 += 32) {
    float4 raw = *(const float4*)(E16 + (ull)(m0 + li) * 256 + k0 + kq * 8);
    const __half* hp = (const __half*)&raw;
#pragma unroll
    for (int i = 0; i < 8; i++) sm.g.As[kq * 8 + i][li] = __half2float(hp[i]);
    const float* gb = attn_w + (ull)(n0 + li) * 512 + k0 + kq * 8;
    const float4 v0 = *(const float4*)gb, v1 = *(const float4*)(gb + 4);
    sm.g.Bs[kq * 8 + 0][li] = v0.x; sm.g.Bs[kq * 8 + 1][li] = v0.y;
    sm.g.Bs[kq * 8 + 2][li] = v0.z; sm.g.Bs[kq * 8 + 3][li] = v0.w;
    sm.g.Bs[kq * 8 + 4][li] = v1.x; sm.g.Bs[kq * 8 + 5][li] = v1.y;
    sm.g.Bs[kq * 8 + 6][li] = v1.z; sm.g.Bs[kq * 8 + 7][li] = v1.w;
    __syncthreads();
#pragma unroll 8
    for (int kk = 0; kk < 32; kk++) {
      const float4 a4 = *(const float4*)&sm.g.As[kk][mq * 4];
      const float4 b4 = *(const float4*)&sm.g.Bs[kk][nq * 4];
      fma16(acc, a4, b4);
    }
    __syncthreads();
  }
#pragma unroll
  for (int i = 0; i < 4; i++) {
    const int m = m0 + mq * 4 + i;
#pragma unroll
    for (int j = 0; j < 2; j++) {
      __half2 h2; h2.x = __float2half(acc[i][j * 2]); h2.y = __float2half(acc[i][j * 2 + 1]);
      stu((unsigned*)(P16 + (ull)m * 256 + n0 + nq * 4) + j, *(unsigned*)&h2);
    }
  }
}

// ---------------------------------------------------------------------------
__global__ __launch_bounds__(256, 1) void seq2seq_pipe(
    const float* __restrict__ src,
    const float* __restrict__ attn_w, const float* __restrict__ attn_b,
    const float* __restrict__ attn_v,
    const float* __restrict__ fc_w, const float* __restrict__ fc_b,
    float* __restrict__ out, int* __restrict__ ib)
{
  __shared__ SMT sm;
  const int blk = blockIdx.x;
  const int tid = threadIdx.x;
  float* fb = (float*)ib + 65536;
  float* y0r  = fb + O_Y0;
  float* h1r  = fb + O_H1;
  float* h0r  = fb + O_H0;
  float* zb   = h0r + BH;          // zeroed by init; overwritten first at dec t=1
  float* ctxb = fb + O_CTX;
  const float* wT0 = fb + O_WT0;
  const float* wT1 = fb + O_WT1;
  const float* wD0 = fb + O_WD0;
  const float* wD1 = fb + O_WD1;
  const float* wdT = fb + O_WDT;
  const float* bp  = fb + O_BP;
  __half* E16 = (__half*)(fb + O_E16);
  __half* P16 = (__half*)(fb + O_P16);
  const int g = blk >> 5, m = blk & 31;
  const int rowg = g * 64;
  int* gf = ib + g * 1024;
  int* ife = gf;             // [0..168]
  int* ifa = gf + 704; int* ifh0 = gf + 736; int* ifh1 = gf + 768; int* ifp = gf + 900;

  const int r = tid & 31, p2 = tid >> 5;
  const int kk4 = tid >> 5, gcq = tid & 31;
  const int bq = tid & 7, ul = tid >> 3;

  // tile geometry (same for both roles): 32 rows x 128 gate-cols
  const int lm = (m < 16) ? m : (m - 16);
  const int row0 = rowg + (lm & 1) * 32;
  const int gc0 = (lm >> 1) * 128;
  const int u = gc0 / 4 + ul;

  float cReg[4] = {0.f, 0.f, 0.f, 0.f};

  // ======== encoder: wavefront, single flag per iter (target 32) ========
  for (int t = 0; t <= SS; t++) {
    flag_wait2(t ? ife + (t - 1) : nullptr, 32, nullptr, 0);
    if (m < 16) {
      if (t < SS) {
        float acc[4][4];
        const float4 bv = *(const float4*)(bp + gc0 + ul * 4);
#pragma unroll
        for (int bd = 0; bd < 4; bd++) { acc[bd][0] = bv.x; acc[bd][1] = bv.y; acc[bd][2] = bv.z; acc[bd][3] = bv.w; }
        {  // x segment (16 k), cached loads (outside pipe loop)
          const int f = tid >> 5;
          sm.a.Hs[f][r]     = src[((ull)(row0 + r) * SS + t) * 16 + f];
          sm.a.Hs[f + 8][r] = src[((ull)(row0 + r) * SS + t) * 16 + f + 8];
        }
        stage_W128h(wT0, gc0, sm.a.Ws);
        __syncthreads();
        comp128(sm.a.Ws, sm.a.Hs, bq, ul, acc, 16);
        __syncthreads();
        const float* ysrc = (t == 0) ? zb : (y0r + (ull)((t + 1) & 1) * BH);
        const float* hb0 = ysrc + (ull)(row0 + r) * 256 + p2 * 2;
        const float* wb = wT0 + 16 * 1024 + kk4 * 4096 + gc0 + gcq * 4;
        gemm_pipe(hb0, hb0, wb, 8, 8, acc, sm);
        lstm_epi(acc, cReg, row0, u, y0r + (ull)(t & 1) * BH, nullptr, 0);
      }
    } else {
      if (t >= 1) {
        const int s = t - 1;
        float acc[4][4];
        const float4 bv = *(const float4*)(bp + 1024 + gc0 + ul * 4);
#pragma unroll
        for (int bd = 0; bd < 4; bd++) { acc[bd][0] = bv.x; acc[bd][1] = bv.y; acc[bd][2] = bv.z; acc[bd][3] = bv.w; }
        const float* ysrc = y0r + (ull)(s & 1) * BH;
        const float* hsrc = (s == 0) ? zb : (h1r + (ull)((s + 1) & 1) * BH);
        const float* hb0 = ysrc + (ull)(row0 + r) * 256 + p2 * 2;
        const float* hb1 = hsrc + (ull)(row0 + r) * 256 + p2 * 2;
        const float* wb = wT1 + kk4 * 4096 + gc0 + gcq * 4;
        gemm_pipe(hb0, hb1, wb, 16, 8, acc, sm);
        lstm_epi(acc, cReg, row0, u, h1r + (ull)(s & 1) * BH, E16, s);
      }
    }
    flag_arrive(ife + t);
  }

  // ======== enc_proj: group-local rows, 21 tiles per block ========
  if (tid == 0) poll(ife + SS, 32);
  __syncthreads();
  {
    const int em0 = rowg * SS;
    for (int tau = m; tau < 672; tau += 32)
      proj_tile(E16, attn_w, P16, em0 + (tau >> 2) * 64, (tau & 3) * 64, sm);
  }
  flag_arrive(ifp);

  // ======== decoder (cReg NOT reset: cell0/cell1 inherit enc-final c0e/c1e
  //          under the identical (row,u) partition) ========
  for (int t = 0; t <= TT; t++) {
    if (t == 0) flag_wait2(ifp, 32, nullptr, 0);
    else flag_wait2(ifh1 + (t - 1), 16, nullptr, 0);
    const int slot = (t + 1) & 1;
    attn_fc(rowg + 2 * m,     t, slot, h1r, wdT, attn_b, attn_v, P16, E16, fc_w, fc_b, ctxb, out, sm);
    attn_fc(rowg + 2 * m + 1, t, slot, h1r, wdT, attn_b, attn_v, P16, E16, fc_w, fc_b, ctxb, out, sm);
    if (t == TT) break;
    flag_arrive(ifa + t);
    if (m < 16) {
      // ---- dec cell0: x = [ctx(256) | h0prev(256) | pred(1)] ----
      flag_wait2(ifa + t, 32, t ? ifh0 + (t - 1) : nullptr, 16);
      float acc[4][4];
      const float4 bv = *(const float4*)(bp + 2048 + gc0 + ul * 4);
#pragma unroll
      for (int bd = 0; bd < 4; bd++) { acc[bd][0] = bv.x; acc[bd][1] = bv.y; acc[bd][2] = bv.z; acc[bd][3] = bv.w; }
      const float* h0src = (t == 0) ? (y0r + BH) : (h0r + (ull)((t + 1) & 1) * BH);
      const float* hb0 = ctxb + (ull)(row0 + r) * 288 + p2 * 2;
      const float* hb1 = h0src + (ull)(row0 + r) * 256 + p2 * 2;
      const float* wb = wD0 + kk4 * 4096 + gc0 + gcq * 4;
      gemm_pipe(hb0, hb1, wb, 16, 8, acc, sm);
      const float4 wp = *(const float4*)(wD0 + 512ull * 1024 + gc0 + ul * 4);
#pragma unroll
      for (int bd = 0; bd < 4; bd++) {
        const int row = row0 + bq * 4 + bd;
        const float p = ld1(ctxb + (ull)row * 288 + 256);
        acc[bd][0] += p * wp.x; acc[bd][1] += p * wp.y; acc[bd][2] += p * wp.z; acc[bd][3] += p * wp.w;
      }
      lstm_epi(acc, cReg, row0, u, h0r + (ull)(t & 1) * BH, nullptr, 0);
      flag_arrive(ifh0 + t);
    } else {
      // ---- dec cell1: x = [h0new(256) | h1prev(256)] ----
      flag_wait2(ifh0 + t, 16, t ? ifh1 + (t - 1) : nullptr, 16);
      float acc[4][4];
      const float4 bv = *(const float4*)(bp + 3072 + gc0 + ul * 4);
#pragma unroll
      for (int bd = 0; bd < 4; bd++) { acc[bd][0] = bv.x; acc[bd][1] = bv.y; acc[bd][2] = bv.z; acc[bd][3] = bv.w; }
      const float* hb0 = h0r + (ull)(t & 1) * BH + (ull)(row0 + r) * 256 + p2 * 2;
      const float* hb1 = h1r + (ull)((t + 1) & 1) * BH + (ull)(row0 + r) * 256 + p2 * 2;
      const float* wb = wD1 + kk4 * 4096 + gc0 + gcq * 4;
      gemm_pipe(hb0, hb1, wb, 16, 8, acc, sm);
      lstm_epi(acc, cReg, row0, u, h1r + (ull)(t & 1) * BH, nullptr, 0);
      flag_arrive(ifh1 + t);
    }
  }
}

// ---------------------------------------------------------------------------
// Init: zero flags + zb, pre-transpose weights (col = u*4+gate), pack biases,
// seed ctx pred col with dec_in0.
// ---------------------------------------------------------------------------
__global__ void init_all(
    const float* __restrict__ src,
    const float* __restrict__ ewih0, const float* __restrict__ ewhh0, const float* __restrict__ eb0,
    const float* __restrict__ ewih1, const float* __restrict__ ewhh1, const float* __restrict__ eb1,
    const float* __restrict__ dwih0, const float* __restrict__ dwhh0, const float* __restrict__ db0,
    const float* __restrict__ dwih1, const float* __restrict__ dwhh1, const float* __restrict__ db1,
    const float* __restrict__ attn_w, int* __restrict__ ib)
{
  const int gid = blockIdx.x * 256 + threadIdx.x;
  const int NG = 1024 * 256;
  float* fb = (float*)ib + 65536;
  for (int i = gid; i < 8192; i += NG) ib[i] = 0;
  for (int i = gid; i < (int)BH; i += NG) fb[O_H0 + BH + i] = 0.f;   // zb
  for (int i = gid; i < 272 * 1024; i += NG) {
    const int k = i >> 10, cg = i & 1023, j = (cg & 3) * 256 + (cg >> 2);
    fb[O_WT0 + i] = (k < 16) ? ewih0[(ull)j * 16 + k] : ewhh0[(ull)j * 256 + k - 16];
  }
  for (int i = gid; i < 512 * 1024; i += NG) {
    const int k = i >> 10, cg = i & 1023, j = (cg & 3) * 256 + (cg >> 2);
    fb[O_WT1 + i] = (k < 256) ? ewih1[(ull)j * 256 + k] : ewhh1[(ull)j * 256 + k - 256];
  }
  for (int i = gid; i < 513 * 1024; i += NG) {
    const int k = i >> 10, cg = i & 1023, j = (cg & 3) * 256 + (cg >> 2);
    float v;
    if (k < 256) v = dwih0[(ull)j * 257 + 1 + k];
    else if (k < 512) v = dwhh0[(ull)j * 256 + k - 256];
    else v = dwih0[(ull)j * 257];
    fb[O_WD0 + i] = v;
  }
  for (int i = gid; i < 512 * 1024; i += NG) {
    const int k = i >> 10, cg = i & 1023, j = (cg & 3) * 256 + (cg >> 2);
    fb[O_WD1 + i] = (k < 256) ? dwih1[(ull)j * 256 + k] : dwhh1[(ull)j * 256 + k - 256];
  }
  for (int i = gid; i < 256 * 256; i += NG) {
    const int k = i >> 8, gg = i & 255;
    fb[O_WDT + i] = attn_w[(ull)gg * 512 + 256 + k];
  }
  for (int i = gid; i < 4096; i += NG) {
    const int set = i >> 10, cg = i & 1023, j = (cg & 3) * 256 + (cg >> 2);
    const float* bsrc = (set == 0) ? eb0 : (set == 1) ? eb1 : (set == 2) ? db0 : db1;
    fb[O_BP + i] = bsrc[j];
  }
  for (int i = gid; i < 512; i += NG)
    fb[O_CTX + (ull)i * 288 + 256] = src[((ull)i * SS + 167) * 16 + 15];
}

extern "C" void kernel_launch(void* const* d_in, const int* in_sizes, int n_in,
                              void* d_out, int out_size, void* d_ws, size_t ws_size,
                              hipStream_t stream)
{
  const float* src    = (const float*)d_in[0];
  const float* ewih0  = (const float*)d_in[1];
  const float* ewhh0  = (const float*)d_in[2];
  const float* eb0    = (const float*)d_in[3];
  const float* ewih1  = (const float*)d_in[4];
  const float* ewhh1  = (const float*)d_in[5];
  const float* eb1    = (const float*)d_in[6];
  const float* dwih0  = (const float*)d_in[7];
  const float* dwhh0  = (const float*)d_in[8];
  const float* db0    = (const float*)d_in[9];
  const float* dwih1  = (const float*)d_in[10];
  const float* dwhh1  = (const float*)d_in[11];
  const float* db1    = (const float*)d_in[12];
  const float* attn_w = (const float*)d_in[13];
  const float* attn_b = (const float*)d_in[14];
  const float* attn_v = (const float*)d_in[15];
  // d_in[16] pos_bias: post-tanh, uniform over s -> softmax-invariant, unused.
  const float* fc_w   = (const float*)d_in[17];
  const float* fc_b   = (const float*)d_in[18];
  float* out = (float*)d_out;
  int* ib    = (int*)d_ws;

  init_all<<<1024, 256, 0, stream>>>(src, ewih0, ewhh0, eb0, ewih1, ewhh1, eb1,
                                     dwih0, dwhh0, db0, dwih1, dwhh1, db1, attn_w, ib);

  void* args[] = {
    (void*)&src, (void*)&attn_w, (void*)&attn_b, (void*)&attn_v,
    (void*)&fc_w, (void*)&fc_b, (void*)&out, (void*)&ib,
  };
  hipLaunchCooperativeKernel((const void*)seq2seq_pipe, dim3(NBLK), dim3(NTHR),
                             args, 0, stream);
}